// Round 1
// baseline (564.206 us; speedup 1.0000x reference)
//
#include <hip/hip_runtime.h>

// ActionThenNodePolicy — MI355X fp32 implementation.
// Structure: 1 block (256 thr = 4 waves) per graph (2048 graphs, 64 nodes, D=256, A=32).
// Phase A: 97 dots/node via LDS-staged values (XOR-swizzled) x SGPR-broadcast weights.
// Phase B: all softmax/segment math in-block (LDS + wave shuffles).

#define NG   2048
#define NEGV -1000000000.0f
#define EPSV 1e-20f

struct WS {
  int flag;          // 1 => mask elements are 4-byte (int32/f32), 0 => 1-byte (bool8)
  int pad[63];
  float Wall[100 * 256]; // row 0: W_node; 1..32: W_agn; 33..64: W_nga; 65..96: 0.5*(Wq[a]+Wq[32+a]); 97..99: 0
};

__global__ void prep_kernel(const unsigned char* __restrict__ atm,
                            const float* __restrict__ Wn,
                            const float* __restrict__ Wagn,
                            const float* __restrict__ Wnga,
                            const float* __restrict__ Wq,
                            WS* __restrict__ ws)
{
  const int t = threadIdx.x;
  const int b = blockIdx.x;
  if (b == 0) {
    __shared__ int s_off, s_max;
    if (t == 0) { s_off = 0; s_max = 0; }
    __syncthreads();
    int loc_off = 0, loc_max = 0;
    for (int i = t; i < 4096; i += 256) {
      int v = atm[i];
      loc_max = max(loc_max, v);
      if ((i & 3) != 0 && v != 0) loc_off = 1;
    }
    if (loc_off) atomicOr(&s_off, 1);
    atomicMax(&s_max, loc_max);
    __syncthreads();
    if (t == 0) {
      // int32 0/1: all bytes at off%4!=0 are 0, max byte 1 -> 4-byte
      // bool8: ~80% ones everywhere -> 1-byte
      // f32 0.0/1.0: bytes 0x80/0x3f present -> max byte >1 -> 4-byte (int read !=0 still correct)
      int f4 = (s_max > 1) ? 1 : (s_off ? 0 : 1);
      ws->flag = f4;
    }
  }
  // build combined weight matrix (16 blocks cooperate)
  for (int e = b * 256 + t; e < 100 * 256; e += 16 * 256) {
    int ro = e >> 8, k = e & 255;
    float w;
    if (ro == 0)       w = Wn[k];
    else if (ro < 33)  w = Wagn[(ro - 1) * 256 + k];
    else if (ro < 65)  w = Wnga[(ro - 33) * 256 + k];
    else if (ro < 97)  w = 0.5f * (Wq[(ro - 65) * 256 + k] + Wq[(ro - 65 + 32) * 256 + k]);
    else               w = 0.f;
    ws->Wall[e] = w;
  }
}

__global__ __launch_bounds__(256, 2) void policy_kernel(
    const int* __restrict__ a_in,
    const float* __restrict__ values,
    const void* __restrict__ atm,
    const void* __restrict__ aam,
    const WS* __restrict__ ws,
    float* __restrict__ out)
{
  // 64 rows x 64 float4 = 65536 B; phase-B arrays alias this after phase A.
  __shared__ float4 vals4[64 * 64];
  float* sm   = (float*)vals4;
  float* nlog = sm;           // 64
  float* agn  = sm + 64;      // 64*33 (pad 33: bank-conflict-free)
  float* nga  = sm + 2176;    // 64*33
  float* qv   = sm + 4288;    // 64*33
  float* pnga = sm + 6400;    // 64*33
  float* pn   = sm + 8512;    // 64
  float* papt = sm + 8576;    // 8*32
  float* pa   = sm + 8832;    // 32
  float* segq = sm + 8864;    // 32
  float* hn   = sm + 8896;    // 32

  const int t = threadIdx.x;
  const int g = blockIdx.x;

  // ---- stage values tile (coalesced float4), XOR-swizzled on float4 column ----
  const float4* src = (const float4*)values + (size_t)g * (64 * 64);
  #pragma unroll
  for (int i = 0; i < 16; ++i) {
    int f = t + (i << 8);
    int n_ = f >> 6, k4 = f & 63;
    vals4[(n_ << 6) + (k4 ^ (n_ & 7))] = src[f];
  }
  __syncthreads();

  // ---- phase A: 25 outputs per wave, weights via wave-uniform scalar loads ----
  const int n = t & 63;
  const int c = __builtin_amdgcn_readfirstlane(threadIdx.x >> 6);
  const int obase = c * 25;
  float acc[25];
  #pragma unroll
  for (int o = 0; o < 25; ++o) acc[o] = 0.f;
  const float4* vrow = vals4 + (n << 6);
  const int swz = n & 7;
  const float* wbase = ws->Wall + obase * 256;
  for (int k4 = 0; k4 < 64; ++k4) {
    float4 v = vrow[k4 ^ swz];
    const float* w = wbase + (k4 << 2);
    #pragma unroll
    for (int o = 0; o < 25; ++o) {
      const float* wo = w + (o << 8);
      float a0 = fmaf(v.x, wo[0], acc[o]);
      a0 = fmaf(v.y, wo[1], a0);
      a0 = fmaf(v.z, wo[2], a0);
      acc[o] = fmaf(v.w, wo[3], a0);
    }
  }
  __syncthreads(); // all vals4 reads done; safe to overwrite with phase-B arrays
  #pragma unroll
  for (int o = 0; o < 25; ++o) {
    int ro = obase + o;
    if (ro == 0)       nlog[n] = acc[o];
    else if (ro < 33)  agn[n * 33 + ro - 1]  = acc[o];
    else if (ro < 65)  nga[n * 33 + ro - 33] = acc[o];
    else if (ro < 97)  qv[n * 33 + ro - 65]  = acc[o];
  }
  __syncthreads();

  const int f4 = ws->flag;
  const size_t mb = (size_t)g * (64 * 32);
  auto mget = [&](const void* p, size_t idx) -> bool {
    return f4 ? (((const int*)p)[idx] != 0)
              : (((const unsigned char*)p)[idx] != 0);
  };

  // ---- B1: p_n = softmax over 64 node logits (wave 0) ----
  if (t < 64) {
    float x = nlog[t];
    float m = x;
    #pragma unroll
    for (int s = 32; s > 0; s >>= 1) m = fmaxf(m, __shfl_xor(m, s));
    float z = expf(x - m);
    float su = z;
    #pragma unroll
    for (int s = 32; s > 0; s >>= 1) su += __shfl_xor(su, s);
    pn[t] = z / su;
  }
  __syncthreads();

  // ---- B2: p_a_given_n softmax (32-lane groups) + p_a partial accumulation ----
  {
    const int aA = t & 31, grp = t >> 5;
    float part = 0.f;
    for (int j = 0; j < 8; ++j) {
      int nn = grp * 8 + j;
      bool mk = mget(atm, mb + (size_t)nn * 32 + aA);
      float l = mk ? agn[nn * 33 + aA] : NEGV;
      float m = l;
      #pragma unroll
      for (int s = 16; s > 0; s >>= 1) m = fmaxf(m, __shfl_xor(m, s));
      float z = expf(l - m);
      float su = z;
      #pragma unroll
      for (int s = 16; s > 0; s >>= 1) su += __shfl_xor(su, s);
      part += pn[nn] * (z / su);
    }
    papt[grp * 32 + aA] = part;
  }

  // ---- B3: p_n__a segment softmax per action column (8-lane groups x 8 nodes) ----
  {
    const int a2 = t >> 3, r = t & 7;
    float lj[8];
    float m = -3.4e38f;
    #pragma unroll
    for (int j = 0; j < 8; ++j) {
      int nn = r * 8 + j;
      size_t mi = mb + (size_t)nn * 32 + a2;
      bool mk = mget(atm, mi) && mget(aam, mi);
      float l = mk ? nga[nn * 33 + a2] : NEGV;
      lj[j] = l;
      m = fmaxf(m, l);
    }
    #pragma unroll
    for (int s = 4; s > 0; s >>= 1) m = fmaxf(m, __shfl_xor(m, s));
    float su = 0.f;
    #pragma unroll
    for (int j = 0; j < 8; ++j) { lj[j] = expf(lj[j] - m); su += lj[j]; }
    #pragma unroll
    for (int s = 4; s > 0; s >>= 1) su += __shfl_xor(su, s);
    float inv = 1.f / su;
    float hq = 0.f, pq = 0.f;
    #pragma unroll
    for (int j = 0; j < 8; ++j) {
      int nn = r * 8 + j;
      float p = lj[j] * inv;
      pnga[nn * 33 + a2] = p;
      hq -= p * logf(p + EPSV);
      pq = fmaf(p, qv[nn * 33 + a2], pq);
    }
    #pragma unroll
    for (int s = 4; s > 0; s >>= 1) { hq += __shfl_xor(hq, s); pq += __shfl_xor(pq, s); }
    if (r == 0) { segq[a2] = pq; hn[a2] = hq; }
  }
  __syncthreads();

  // ---- B4: finalize p_a, value, entropy, logprob (wave 0) + write p_n__a ----
  if (t < 32) {
    float s0 = 0.f;
    #pragma unroll
    for (int gq = 0; gq < 8; ++gq) s0 += papt[gq * 32 + t];
    pa[t] = s0;
    out[6144 + g * 32 + t] = s0; // p_a
    float v1 = s0 * segq[t];
    float e1 = -s0 * logf(s0 + EPSV);
    float e2 = s0 * hn[t];
    #pragma unroll
    for (int s = 16; s > 0; s >>= 1) {
      v1 += __shfl_xor(v1, s);
      e1 += __shfl_xor(e1, s);
      e2 += __shfl_xor(e2, s);
    }
    if (t == 0) {
      out[4096 + g] = v1;        // value
      out[2048 + g] = e1 + e2;   // entropy
      int act = a_in[g * 2 + 0];
      int anl = a_in[g * 2 + 1] - g * 64;
      out[g] = logf(pa[act] + EPSV) + logf(pnga[anl * 33 + act] + EPSV); // logprob
    }
  }
  const size_t ob = 71680 + (size_t)g * 2048;
  #pragma unroll
  for (int i = 0; i < 8; ++i) {
    int e = t + (i << 8);
    out[ob + e] = pnga[(e >> 5) * 33 + (e & 31)];
  }
}

extern "C" void kernel_launch(void* const* d_in, const int* in_sizes, int n_in,
                              void* d_out, int out_size, void* d_ws, size_t ws_size,
                              hipStream_t stream)
{
  const int*   a_in   = (const int*)d_in[0];
  const float* values = (const float*)d_in[1];
  const void*  atm    = d_in[3];
  const void*  aam    = d_in[4];
  const float* Wn     = (const float*)d_in[6];
  const float* Wagn   = (const float*)d_in[7];
  const float* Wnga   = (const float*)d_in[8];
  const float* Wq     = (const float*)d_in[9];
  WS*    ws  = (WS*)d_ws;
  float* out = (float*)d_out;

  hipLaunchKernelGGL(prep_kernel, dim3(16), dim3(256), 0, stream,
                     (const unsigned char*)atm, Wn, Wagn, Wnga, Wq, ws);
  hipLaunchKernelGGL(policy_kernel, dim3(NG), dim3(256), 0, stream,
                     a_in, values, atm, aam, ws, out);
}